// Round 1
// baseline (58.261 us; speedup 1.0000x reference)
//
#include <hip/hip_runtime.h>
#include <math.h>

#define NB       128   // batch
#define SEQ      400   // feature sequence length
#define DIN      256   // feature dim
#define HID      128   // hidden dim (DIN/2)
#define NE       6     // experts
#define NQ       300   // queries
#define NC       6     // classes
#define NROW     300   // rows used per batch = min(SEQ, NQ)
#define ROWS_BLK 64
#define THREADS  512
#define DCHUNK   64
#define FT_STRIDE 68   // padded stride for transposed feature tile [d][row]
#define H_STRIDE  132  // padded stride for h tile [row][j]
#define FT_OFF   8192  // word offset of feature tile within s_mem
#define OUT_BBOX_SZ (NB * NQ * 4)   // 153600

// s_mem layout:
//   during GEMM chunks: [0..8191] = W1 chunk [64][128], [8192..12543] = ft [64][68]
//   during epilogue:    [0..8447] = h tile [64][132]  (aliased; barrier-separated)
__global__ __launch_bounds__(THREADS)
void moe_fused_kernel(const float* __restrict__ features,
                      const float* __restrict__ W1,
                      const float* __restrict__ b1,
                      const float* __restrict__ W2,
                      const float* __restrict__ b2,
                      const float* __restrict__ ebox,
                      const float* __restrict__ ecls,
                      float* __restrict__ out)
{
    __shared__ float s_mem[12544];
    __shared__ float s_w2[HID * NE];

    const int t    = (int)threadIdx.x;
    const int row0 = (int)blockIdx.x * ROWS_BLK;

    // stage W2 once (tiny)
    for (int i = t; i < HID * NE; i += THREADS) s_w2[i] = W2[i];

    const int rg = t >> 5;   // 0..15 : row group (4 rows each)
    const int cg = t & 31;   // 0..31 : col group (4 cols each)

    float4 acc0 = make_float4(0.f, 0.f, 0.f, 0.f);
    float4 acc1 = acc0, acc2 = acc0, acc3 = acc0;

    for (int c = 0; c < DIN / DCHUNK; ++c) {
        const int d0 = c * DCHUNK;
        __syncthreads();  // protect previous chunk's LDS reads
        // ---- stage W1 chunk: 64 rows x 128 cols, contiguous copy ----
        {
            const float4* src = (const float4*)(W1 + (size_t)d0 * HID);
            float4* dst = (float4*)s_mem;
            #pragma unroll
            for (int i = 0; i < 4; ++i)
                dst[i * THREADS + t] = src[i * THREADS + t];
        }
        // ---- stage features transposed: ft[d][row], 64 rows x 64 d ----
        {
            float* ft = s_mem + FT_OFF;
            #pragma unroll
            for (int i = 0; i < 2; ++i) {
                int idx = i * THREADS + t;        // float4 index, 1024 total
                int r   = idx >> 4;               // 0..63 (local row)
                int dd  = (idx & 15) << 2;        // 0,4,...,60
                int rowg = row0 + r;
                int bb = rowg / NROW;
                int ss = rowg - bb * NROW;
                const float* fp = features + (size_t)(bb * SEQ + ss) * DIN + d0 + dd;
                float4 v = *(const float4*)fp;
                ft[(dd + 0) * FT_STRIDE + r] = v.x;
                ft[(dd + 1) * FT_STRIDE + r] = v.y;
                ft[(dd + 2) * FT_STRIDE + r] = v.z;
                ft[(dd + 3) * FT_STRIDE + r] = v.w;
            }
        }
        __syncthreads();
        // ---- main loop: h[r0..r0+3][j0..j0+3] accumulate over 64 d ----
        const float* wp = s_mem + cg * 4;
        const float* fp = s_mem + FT_OFF + rg * 4;
        #pragma unroll 8
        for (int d = 0; d < DCHUNK; ++d) {
            float4 w = *(const float4*)(wp + d * HID);
            float4 f = *(const float4*)(fp + d * FT_STRIDE);
            acc0.x += f.x * w.x; acc0.y += f.x * w.y; acc0.z += f.x * w.z; acc0.w += f.x * w.w;
            acc1.x += f.y * w.x; acc1.y += f.y * w.y; acc1.z += f.y * w.z; acc1.w += f.y * w.w;
            acc2.x += f.z * w.x; acc2.y += f.z * w.y; acc2.z += f.z * w.z; acc2.w += f.z * w.w;
            acc3.x += f.w * w.x; acc3.y += f.w * w.y; acc3.z += f.w * w.z; acc3.w += f.w * w.w;
        }
    }

    // ---- bias + relu, store h tile to LDS (aliases W1/ft region) ----
    const float4 bias = *(const float4*)(b1 + cg * 4);
    __syncthreads();
    {
        const int jw = cg * 4;
        float* hb = s_mem;
        float4 h;
        h.x = fmaxf(acc0.x + bias.x, 0.f); h.y = fmaxf(acc0.y + bias.y, 0.f);
        h.z = fmaxf(acc0.z + bias.z, 0.f); h.w = fmaxf(acc0.w + bias.w, 0.f);
        *(float4*)(hb + (size_t)(rg * 4 + 0) * H_STRIDE + jw) = h;
        h.x = fmaxf(acc1.x + bias.x, 0.f); h.y = fmaxf(acc1.y + bias.y, 0.f);
        h.z = fmaxf(acc1.z + bias.z, 0.f); h.w = fmaxf(acc1.w + bias.w, 0.f);
        *(float4*)(hb + (size_t)(rg * 4 + 1) * H_STRIDE + jw) = h;
        h.x = fmaxf(acc2.x + bias.x, 0.f); h.y = fmaxf(acc2.y + bias.y, 0.f);
        h.z = fmaxf(acc2.z + bias.z, 0.f); h.w = fmaxf(acc2.w + bias.w, 0.f);
        *(float4*)(hb + (size_t)(rg * 4 + 2) * H_STRIDE + jw) = h;
        h.x = fmaxf(acc3.x + bias.x, 0.f); h.y = fmaxf(acc3.y + bias.y, 0.f);
        h.z = fmaxf(acc3.z + bias.z, 0.f); h.w = fmaxf(acc3.w + bias.w, 0.f);
        *(float4*)(hb + (size_t)(rg * 4 + 3) * H_STRIDE + jw) = h;
    }
    __syncthreads();

    // ---- logits: 8 threads per row, 16 d each ----
    const int lrow = t >> 3;   // 0..63
    const int part = t & 7;    // 0..7
    float l0 = 0.f, l1 = 0.f, l2 = 0.f, l3 = 0.f, l4 = 0.f, l5 = 0.f;
    {
        const float* hp  = s_mem + (size_t)lrow * H_STRIDE + part * 16;
        const float* w2p = s_w2 + part * 16 * NE;
        #pragma unroll
        for (int k = 0; k < 16; ++k) {
            float hv = hp[k];
            l0 += hv * w2p[k * NE + 0];
            l1 += hv * w2p[k * NE + 1];
            l2 += hv * w2p[k * NE + 2];
            l3 += hv * w2p[k * NE + 3];
            l4 += hv * w2p[k * NE + 4];
            l5 += hv * w2p[k * NE + 5];
        }
    }
    #pragma unroll
    for (int off = 1; off < 8; off <<= 1) {
        l0 += __shfl_xor(l0, off);
        l1 += __shfl_xor(l1, off);
        l2 += __shfl_xor(l2, off);
        l3 += __shfl_xor(l3, off);
        l4 += __shfl_xor(l4, off);
        l5 += __shfl_xor(l5, off);
    }

    if (part == 0) {
        float lg[NE];
        lg[0] = l0 + b2[0]; lg[1] = l1 + b2[1]; lg[2] = l2 + b2[2];
        lg[3] = l3 + b2[3]; lg[4] = l4 + b2[4]; lg[5] = l5 + b2[5];
        float m = lg[0];
        #pragma unroll
        for (int e = 1; e < NE; ++e) m = fmaxf(m, lg[e]);
        float p[NE];
        float psum = 0.f;
        #pragma unroll
        for (int e = 0; e < NE; ++e) { p[e] = expf(lg[e] - m); psum += p[e]; }
        #pragma unroll
        for (int e = 0; e < NE; ++e) p[e] = p[e] / psum;

        // top-2 on softmax probs, stable tie-break (lower index wins) = lax.top_k
        int i0 = 0; float v0 = p[0];
        #pragma unroll
        for (int e = 1; e < NE; ++e) if (p[e] > v0) { v0 = p[e]; i0 = e; }
        int i1 = -1; float v1 = -1e38f;
        #pragma unroll
        for (int e = 0; e < NE; ++e) if (e != i0 && p[e] > v1) { v1 = p[e]; i1 = e; }

        // routing weights = softmax([v0, v1]) (v0 is the max)
        float e1  = expf(v1 - v0);
        float ssum = 1.f + e1;
        float rw0 = 1.f / ssum;
        float rw1 = e1 / ssum;

        int rowg = row0 + lrow;
        int bb = rowg / NROW;
        int ss = rowg - bb * NROW;

        // bboxes: gather 2 experts, blend, write 4 floats
        size_t bo0 = ((size_t)(i0 * NB + bb) * NQ + ss) * 4;
        size_t bo1 = ((size_t)(i1 * NB + bb) * NQ + ss) * 4;
        float4 g0 = *(const float4*)(ebox + bo0);
        float4 g1 = *(const float4*)(ebox + bo1);
        float4 ob;
        ob.x = rw0 * g0.x + rw1 * g1.x;
        ob.y = rw0 * g0.y + rw1 * g1.y;
        ob.z = rw0 * g0.z + rw1 * g1.z;
        ob.w = rw0 * g0.w + rw1 * g1.w;
        *(float4*)(out + (size_t)rowg * 4) = ob;

        // class scores: gather 2 experts, blend, write 6 floats
        size_t co0 = ((size_t)(i0 * NB + bb) * NQ + ss) * NC;
        size_t co1 = ((size_t)(i1 * NB + bb) * NQ + ss) * NC;
        float* oc = out + OUT_BBOX_SZ + (size_t)rowg * NC;
        #pragma unroll
        for (int k = 0; k < NC; ++k)
            oc[k] = rw0 * ecls[co0 + k] + rw1 * ecls[co1 + k];
    }
}

extern "C" void kernel_launch(void* const* d_in, const int* in_sizes, int n_in,
                              void* d_out, int out_size, void* d_ws, size_t ws_size,
                              hipStream_t stream)
{
    const float* features = (const float*)d_in[0];
    const float* W1   = (const float*)d_in[1];
    const float* b1   = (const float*)d_in[2];
    const float* W2   = (const float*)d_in[3];
    const float* b2   = (const float*)d_in[4];
    const float* ebox = (const float*)d_in[5];
    const float* ecls = (const float*)d_in[6];
    float* out = (float*)d_out;

    dim3 grid((NB * NROW) / ROWS_BLK);  // 600 blocks
    dim3 block(THREADS);
    hipLaunchKernelGGL(moe_fused_kernel, grid, block, 0, stream,
                       features, W1, b1, W2, b2, ebox, ecls, out);
}